// Round 16
// baseline (792.169 us; speedup 1.0000x reference)
//
#include <hip/hip_runtime.h>
#include <hip/hip_bf16.h>
#include <math.h>

// Problem constants
#define BB   64
#define TT   2048
#define DD   8        // LATENT
#define HH   64       // HID
#define LLEN 2046     // length = TT - LAGS
#define NN   (BB*LLEN) // 130944 = 32*4092
#define GIN  81       // HID + LAGS*LATENT + 1

#define NG   (NN/32)  // 4092 sample-groups of 32
#define WPB  8        // waves per block (512 threads)
#define GPW  4        // groups per wave (register-prefetch pipeline)
#define ZSTR 36       // padded LDS row stride (dwords, 16B-aligned)

// swizzled LDS offset: row-major [128][ZSTR], s-block slot rotated by row>>3
// (HW-validated: 1.05M conflict-cycles total — do not change)
__device__ __forceinline__ int zoff(int row, int sb) {
    return row * ZSTR + (((sb + (row >> 3)) & 7) << 2);
}

// ---------------------------------------------------------------------------
// Embedding MLP: thread per (b,t); writes embT[g][k][s] (k-major, 32-sample
// groups) so gmlp can stage coalesced without a transpose.
// ---------------------------------------------------------------------------
template<int K, bool ACT>
__device__ __forceinline__ void fwd_layer(float* zr,
                                          const float* __restrict__ W,
                                          const float* __restrict__ bias)
{
    float acc[HH];
#pragma unroll
    for (int j = 0; j < HH; ++j) acc[j] = bias[j];
    for (int k = 0; k < K; ++k) {
        const float zk = zr[k];
        const float* wr = W + k * HH;
#pragma unroll
        for (int j = 0; j < HH; ++j) acc[j] = fmaf(zk, wr[j], acc[j]);
    }
#pragma unroll
    for (int j = 0; j < HH; ++j) {
        float v = acc[j];
        if (ACT) v = (v >= 0.f) ? v : 0.1f * v;
        zr[j] = v;
    }
}

__global__ __launch_bounds__(192) void emb_mlp_kernel(
    const float* __restrict__ emb_in,
    const float* __restrict__ W1, const float* __restrict__ b1,
    const float* __restrict__ Wh, const float* __restrict__ bh,
    const float* __restrict__ W2, const float* __restrict__ b2,
    float* __restrict__ embT)
{
    __shared__ float zrow[192][65];
    const int tid = threadIdx.x;
    const int n = blockIdx.x * 192 + tid;          // 682*192 == NN exact
    const int b = n / LLEN;
    const int l = n - b * LLEN;
    float* zr = zrow[tid];

    const float* ep = emb_in + ((size_t)(b * TT + (l + 2))) * 8;
    {
        float4 e0 = *(const float4*)ep;
        float4 e1 = *(const float4*)(ep + 4);
        zr[0] = e0.x; zr[1] = e0.y; zr[2] = e0.z; zr[3] = e0.w;
        zr[4] = e1.x; zr[5] = e1.y; zr[6] = e1.z; zr[7] = e1.w;
    }

    fwd_layer<8,  true >(zr, W1, b1);
    fwd_layer<HH, true >(zr, Wh,            bh);
    fwd_layer<HH, true >(zr, Wh + HH * HH,  bh + HH);
    fwd_layer<HH, false>(zr, W2, b2);

    // embT[n>>5][k][n&31] — per k, 32 consecutive threads write 128B chunks
    float* op = embT + ((size_t)(n >> 5)) * 2048 + (n & 31);
#pragma unroll
    for (int j = 0; j < HH; ++j) op[j * 32] = zr[j];
}

// ---------------------------------------------------------------------------
// gmlp: one wave processes GPW consecutive 32-sample groups (for block's d).
// Lane (sg,jg) owns a 4-sample x 8-neuron tile; per k: 1 z-quad + 1 dz-quad
// from swizzled LDS + 2 weight float4s from GLOBAL (L1-resident broadcast).
// Next group's inputs prefetched into REGISTERS after the L1 phase — global
// latency hides under H1+H2; the LDS rewrite waits for H2's reads via the
// in-order same-address DS pipe. No barriers; waves autonomous.
// Bit-identical arithmetic to rounds 4/10/12 (absmax 0.25).
// ---------------------------------------------------------------------------
__global__ __launch_bounds__(WPB * 64, 1) void gmlp_kernel(
    const float* __restrict__ x,
    const float* __restrict__ embT,
    const float* __restrict__ gW1, const float* __restrict__ gb1,
    const float* __restrict__ gWh, const float* __restrict__ gbh,
    const float* __restrict__ gW2, const float* __restrict__ gb2,
    float* __restrict__ resid, float* __restrict__ logd)
{
    __shared__ __align__(16) float zb[WPB][128 * ZSTR];   // 8*18432 B = 147456 B
    // -> 1 block/CU, 8 waves (2 per SIMD)

    const int tid  = threadIdx.x;
    const int lane = tid & 63;
    const int w    = tid >> 6;
    const int d    = blockIdx.y;
    const int g0   = (blockIdx.x * WPB + w) * GPW;   // 128 blocks/d * 8 * 4 = 4096 slots

    float* Z = zb[w];
    const int sg = lane >> 3;   // s-block (4 samples each)
    const int jg = lane & 7;    // j-block (8 neurons each)

    // ---- loop-invariant weight/bias bases ----
    const float* W1 = gW1 + (size_t)d * GIN * HH + jg * 8;
    const float* Whg = gWh + (size_t)d * 2 * HH * HH;
    const float4 b1a = *(const float4*)&gb1[d * HH + jg * 8];
    const float4 b1b = *(const float4*)&gb1[d * HH + jg * 8 + 4];
    const float4 bh0a = *(const float4*)&gbh[(d * 2 + 0) * HH + jg * 8];
    const float4 bh0b = *(const float4*)&gbh[(d * 2 + 0) * HH + jg * 8 + 4];
    const float4 bh1a = *(const float4*)&gbh[(d * 2 + 1) * HH + jg * 8];
    const float4 bh1b = *(const float4*)&gbh[(d * 2 + 1) * HH + jg * 8 + 4];
    const float4 w2a = *(const float4*)&gW2[d * HH + jg * 8];
    const float4 w2b = *(const float4*)&gW2[d * HH + jg * 8 + 4];
    const float b2 = gb2[d];

    // ---- register prefetch state (one group ahead) ----
    float4 pe[8];           // emb rows (k-major quads)
    float  pxv[8], pxt;     // lag elements + x_t
    const int s_ = lane & 31, h_ = lane >> 5;

    auto issue_loads = [&](int gid) {
        const float* eb = embT + (size_t)gid * 2048;
#pragma unroll
        for (int i = 0; i < 8; ++i)
            pe[i] = *(const float4*)&eb[i * 256 + lane * 4];
        const int n = gid * 32 + s_;
        const int b = n / LLEN, l = n - b * LLEN;
        const float* xp = x + ((size_t)(b * TT + l)) * DD;
        float4 xv0 = *(const float4*)(xp + h_ * 8);
        float4 xv1 = *(const float4*)(xp + h_ * 8 + 4);
        pxv[0] = xv0.x; pxv[1] = xv0.y; pxv[2] = xv0.z; pxv[3] = xv0.w;
        pxv[4] = xv1.x; pxv[5] = xv1.y; pxv[6] = xv1.z; pxv[7] = xv1.w;
        pxt = xp[16 + d];                        // valid for all lanes
    };
    auto write_zin = [&]() {
#pragma unroll
        for (int i = 0; i < 8; ++i) {
            const int row = i * 8 + (lane >> 3);
            *(float4*)&Z[zoff(row, lane & 7)] = pe[i];
        }
#pragma unroll
        for (int r = 0; r < 8; ++r) {
            const int R = 64 + h_ * 8 + r;
            Z[zoff(R, s_ >> 2) + (s_ & 3)] = pxv[r];
        }
        if (h_ == 0) Z[zoff(80, s_ >> 2) + (s_ & 3)] = pxt;
    };

    if (g0 < NG) issue_loads(g0);

    for (int g = 0; g < GPW; ++g) {
        const int gid = g0 + g;
        if (gid >= NG) break;                    // wave-uniform
        const int n0 = gid * 32;

        write_zin();                             // current group's staged regs -> Z

        // ---- L1: 81 -> 64, forward only ----
        float f[4][8];
#pragma unroll
        for (int si = 0; si < 4; ++si) {
            f[si][0] = b1a.x; f[si][1] = b1a.y; f[si][2] = b1a.z; f[si][3] = b1a.w;
            f[si][4] = b1b.x; f[si][5] = b1b.y; f[si][6] = b1b.z; f[si][7] = b1b.w;
        }
        __builtin_amdgcn_s_setprio(1);
#pragma unroll 8
        for (int k = 0; k < GIN; ++k) {
            const float4 wa = *(const float4*)&W1[(size_t)k * HH];
            const float4 wb = *(const float4*)&W1[(size_t)k * HH + 4];
            const float4 zq = *(const float4*)&Z[zoff(k, sg)];
            const float zs[4] = { zq.x, zq.y, zq.z, zq.w };
#pragma unroll
            for (int si = 0; si < 4; ++si) {
                f[si][0] = fmaf(zs[si], wa.x, f[si][0]);
                f[si][1] = fmaf(zs[si], wa.y, f[si][1]);
                f[si][2] = fmaf(zs[si], wa.z, f[si][2]);
                f[si][3] = fmaf(zs[si], wa.w, f[si][3]);
                f[si][4] = fmaf(zs[si], wb.x, f[si][4]);
                f[si][5] = fmaf(zs[si], wb.y, f[si][5]);
                f[si][6] = fmaf(zs[si], wb.z, f[si][6]);
                f[si][7] = fmaf(zs[si], wb.w, f[si][7]);
            }
        }
        __builtin_amdgcn_s_setprio(0);

        // ---- act + JVP seed; transpose-publish z (rows j), dz (rows 64+j) ----
        {
            const float4 w80a = *(const float4*)&W1[80 * HH];
            const float4 w80b = *(const float4*)&W1[80 * HH + 4];
            const float w80[8] = { w80a.x, w80a.y, w80a.z, w80a.w,
                                   w80b.x, w80b.y, w80b.z, w80b.w };
            float zv[4][8], dv[4][8];
#pragma unroll
            for (int si = 0; si < 4; ++si)
#pragma unroll
                for (int jj = 0; jj < 8; ++jj) {
                    const float m = (f[si][jj] >= 0.f) ? 1.f : 0.1f;
                    zv[si][jj] = f[si][jj] * m;
                    dv[si][jj] = w80[jj] * m;
                }
#pragma unroll
            for (int jj = 0; jj < 8; ++jj) {
                const int row = jg * 8 + jj;
                float4 q = { zv[0][jj], zv[1][jj], zv[2][jj], zv[3][jj] };
                *(float4*)&Z[zoff(row, sg)] = q;
                float4 p = { dv[0][jj], dv[1][jj], dv[2][jj], dv[3][jj] };
                *(float4*)&Z[zoff(64 + row, sg)] = p;
            }
        }

        // ---- prefetch next group's inputs (latency hides under H1+H2) ----
        if (g + 1 < GPW && gid + 1 < NG) issue_loads(gid + 1);

        // ---- hidden layers: fused forward + JVP ----
        float ff[4][8], dd[4][8];
#pragma unroll
        for (int hl = 0; hl < 2; ++hl) {
            const float* Wl = Whg + hl * (HH * HH) + jg * 8;
            const float4 ba = hl ? bh1a : bh0a;
            const float4 bb = hl ? bh1b : bh0b;
#pragma unroll
            for (int si = 0; si < 4; ++si) {
                ff[si][0] = ba.x; ff[si][1] = ba.y; ff[si][2] = ba.z; ff[si][3] = ba.w;
                ff[si][4] = bb.x; ff[si][5] = bb.y; ff[si][6] = bb.z; ff[si][7] = bb.w;
#pragma unroll
                for (int jj = 0; jj < 8; ++jj) dd[si][jj] = 0.f;
            }
            __builtin_amdgcn_s_setprio(1);
#pragma unroll 8
            for (int k = 0; k < HH; ++k) {
                const float4 wa = *(const float4*)&Wl[k * HH];
                const float4 wb = *(const float4*)&Wl[k * HH + 4];
                const float4 zq = *(const float4*)&Z[zoff(k, sg)];
                const float4 dq = *(const float4*)&Z[zoff(64 + k, sg)];
                const float zs[4] = { zq.x, zq.y, zq.z, zq.w };
                const float ds[4] = { dq.x, dq.y, dq.z, dq.w };
#pragma unroll
                for (int si = 0; si < 4; ++si) {
                    ff[si][0] = fmaf(zs[si], wa.x, ff[si][0]);  dd[si][0] = fmaf(ds[si], wa.x, dd[si][0]);
                    ff[si][1] = fmaf(zs[si], wa.y, ff[si][1]);  dd[si][1] = fmaf(ds[si], wa.y, dd[si][1]);
                    ff[si][2] = fmaf(zs[si], wa.z, ff[si][2]);  dd[si][2] = fmaf(ds[si], wa.z, dd[si][2]);
                    ff[si][3] = fmaf(zs[si], wa.w, ff[si][3]);  dd[si][3] = fmaf(ds[si], wa.w, dd[si][3]);
                    ff[si][4] = fmaf(zs[si], wb.x, ff[si][4]);  dd[si][4] = fmaf(ds[si], wb.x, dd[si][4]);
                    ff[si][5] = fmaf(zs[si], wb.y, ff[si][5]);  dd[si][5] = fmaf(ds[si], wb.y, dd[si][5]);
                    ff[si][6] = fmaf(zs[si], wb.z, ff[si][6]);  dd[si][6] = fmaf(ds[si], wb.z, dd[si][6]);
                    ff[si][7] = fmaf(zs[si], wb.w, ff[si][7]);  dd[si][7] = fmaf(ds[si], wb.w, dd[si][7]);
                }
            }
            __builtin_amdgcn_s_setprio(0);
            // activation (in place)
#pragma unroll
            for (int si = 0; si < 4; ++si)
#pragma unroll
                for (int jj = 0; jj < 8; ++jj) {
                    const float m = (ff[si][jj] >= 0.f) ? 1.f : 0.1f;
                    ff[si][jj] *= m;
                    dd[si][jj] *= m;
                }
            if (hl == 0) {   // republish for H2
#pragma unroll
                for (int jj = 0; jj < 8; ++jj) {
                    const int row = jg * 8 + jj;
                    float4 q = { ff[0][jj], ff[1][jj], ff[2][jj], ff[3][jj] };
                    *(float4*)&Z[zoff(row, sg)] = q;
                    float4 p = { dd[0][jj], dd[1][jj], dd[2][jj], dd[3][jj] };
                    *(float4*)&Z[zoff(64 + row, sg)] = p;
                }
            }
        }

        // ---- final layer: 64 -> 1 (reduce over jg lanes) ----
        {
            float o[4], q[4];
#pragma unroll
            for (int si = 0; si < 4; ++si) {
                o[si] = ff[si][0]*w2a.x + ff[si][1]*w2a.y + ff[si][2]*w2a.z + ff[si][3]*w2a.w
                      + ff[si][4]*w2b.x + ff[si][5]*w2b.y + ff[si][6]*w2b.z + ff[si][7]*w2b.w;
                q[si] = dd[si][0]*w2a.x + dd[si][1]*w2a.y + dd[si][2]*w2a.z + dd[si][3]*w2a.w
                      + dd[si][4]*w2b.x + dd[si][5]*w2b.y + dd[si][6]*w2b.z + dd[si][7]*w2b.w;
#pragma unroll
                for (int m = 1; m <= 4; m <<= 1) {
                    o[si] += __shfl_xor(o[si], m);
                    q[si] += __shfl_xor(q[si], m);
                }
            }
            if (jg == 0) {
                const int nb = n0 + sg * 4;
                float4 lq;
                lq.x = __logf(fabsf(q[0])); lq.y = __logf(fabsf(q[1]));
                lq.z = __logf(fabsf(q[2])); lq.w = __logf(fabsf(q[3]));
#pragma unroll
                for (int si = 0; si < 4; ++si)
                    resid[(size_t)(nb + si) * DD + d] = o[si] + b2;
                *(float4*)&logd[(size_t)d * NN + nb] = lq;
            }
        }
    }
}

// ---------------------------------------------------------------------------
// log-det reduction over d
// ---------------------------------------------------------------------------
__global__ __launch_bounds__(256) void reduce_kernel(
    const float* __restrict__ logd, float* __restrict__ out)
{
    const int n = blockIdx.x * 256 + threadIdx.x;
    if (n >= NN) return;
    float s = 0.f;
#pragma unroll
    for (int d = 0; d < DD; ++d) s += logd[(size_t)d * NN + n];
    out[n] = s;
}

extern "C" void kernel_launch(void* const* d_in, const int* in_sizes, int n_in,
                              void* d_out, int out_size, void* d_ws, size_t ws_size,
                              hipStream_t stream)
{
    const float* x          = (const float*)d_in[0];
    const float* embeddings = (const float*)d_in[1];
    const float* fcW1 = (const float*)d_in[2];
    const float* fcb1 = (const float*)d_in[3];
    const float* fcWh = (const float*)d_in[4];
    const float* fcbh = (const float*)d_in[5];
    const float* fcW2 = (const float*)d_in[6];
    const float* fcb2 = (const float*)d_in[7];
    const float* gW1  = (const float*)d_in[8];
    const float* gb1  = (const float*)d_in[9];
    const float* gWh  = (const float*)d_in[10];
    const float* gbh  = (const float*)d_in[11];
    const float* gW2  = (const float*)d_in[12];
    const float* gb2  = (const float*)d_in[13];

    float* out  = (float*)d_out;
    float* embT = (float*)d_ws;                         // NN*64 floats (k-major groups)
    float* logd = embT + (size_t)NN * HH;               // NN*8 floats

    emb_mlp_kernel<<<dim3(NN / 192), 192, 0, stream>>>(
        embeddings, fcW1, fcb1, fcWh, fcbh, fcW2, fcb2, embT);

    // 128 blocks/d x 8 waves x 4 groups = 4096 group-slots >= 4092
    gmlp_kernel<<<dim3((NG + WPB * GPW - 1) / (WPB * GPW), DD), WPB * 64, 0, stream>>>(
        x, embT, gW1, gb1, gWh, gbh, gW2, gb2, out, logd);

    reduce_kernel<<<dim3((NN + 255) / 256), 256, 0, stream>>>(
        logd, out + (size_t)NN * DD);
}

// Round 17
// 723.139 us; speedup vs baseline: 1.0955x; 1.0955x over previous
//
#include <hip/hip_runtime.h>
#include <hip/hip_bf16.h>
#include <math.h>

// Problem constants
#define BB   64
#define TT   2048
#define DD   8        // LATENT
#define HH   64       // HID
#define LLEN 2046     // length = TT - LAGS
#define NN   (BB*LLEN) // 130944 = 32*4092
#define GIN  81       // HID + LAGS*LATENT + 1

#define NG   (NN/32)  // 4092 sample-groups of 32
#define WPB  8        // waves per block (512 threads)
#define GPW  4        // groups per wave (register-prefetch pipeline)
#define ZSTR 36       // padded LDS row stride (dwords, 16B-aligned)

// swizzled LDS offset: row-major [128][ZSTR], s-block slot rotated by row>>3
// (HW-validated: 1.05M conflict-cycles total — do not change)
__device__ __forceinline__ int zoff(int row, int sb) {
    return row * ZSTR + (((sb + (row >> 3)) & 7) << 2);
}

// ---------------------------------------------------------------------------
// Embedding MLP: thread per (b,t); writes embT[g][k][s] (k-major, 32-sample
// groups) so gmlp can stage coalesced without a transpose.
// ---------------------------------------------------------------------------
template<int K, bool ACT>
__device__ __forceinline__ void fwd_layer(float* zr,
                                          const float* __restrict__ W,
                                          const float* __restrict__ bias)
{
    float acc[HH];
#pragma unroll
    for (int j = 0; j < HH; ++j) acc[j] = bias[j];
    for (int k = 0; k < K; ++k) {
        const float zk = zr[k];
        const float* wr = W + k * HH;
#pragma unroll
        for (int j = 0; j < HH; ++j) acc[j] = fmaf(zk, wr[j], acc[j]);
    }
#pragma unroll
    for (int j = 0; j < HH; ++j) {
        float v = acc[j];
        if (ACT) v = (v >= 0.f) ? v : 0.1f * v;
        zr[j] = v;
    }
}

__global__ __launch_bounds__(192) void emb_mlp_kernel(
    const float* __restrict__ emb_in,
    const float* __restrict__ W1, const float* __restrict__ b1,
    const float* __restrict__ Wh, const float* __restrict__ bh,
    const float* __restrict__ W2, const float* __restrict__ b2,
    float* __restrict__ embT)
{
    __shared__ float zrow[192][65];
    const int tid = threadIdx.x;
    const int n = blockIdx.x * 192 + tid;          // 682*192 == NN exact
    const int b = n / LLEN;
    const int l = n - b * LLEN;
    float* zr = zrow[tid];

    const float* ep = emb_in + ((size_t)(b * TT + (l + 2))) * 8;
    {
        float4 e0 = *(const float4*)ep;
        float4 e1 = *(const float4*)(ep + 4);
        zr[0] = e0.x; zr[1] = e0.y; zr[2] = e0.z; zr[3] = e0.w;
        zr[4] = e1.x; zr[5] = e1.y; zr[6] = e1.z; zr[7] = e1.w;
    }

    fwd_layer<8,  true >(zr, W1, b1);
    fwd_layer<HH, true >(zr, Wh,            bh);
    fwd_layer<HH, true >(zr, Wh + HH * HH,  bh + HH);
    fwd_layer<HH, false>(zr, W2, b2);

    // embT[n>>5][k][n&31] — per k, 32 consecutive threads write 128B chunks
    float* op = embT + ((size_t)(n >> 5)) * 2048 + (n & 31);
#pragma unroll
    for (int j = 0; j < HH; ++j) op[j * 32] = zr[j];
}

// ---------------------------------------------------------------------------
// gmlp: one wave processes GPW consecutive 32-sample groups (for block's d).
// Lane (sg,jg) owns a 4-sample x 8-neuron tile; per k: 1 z-quad + 1 dz-quad
// from swizzled LDS + 2 weight float4s from GLOBAL (L1-resident broadcast).
// Next group's inputs prefetched into NAMED float4 REGISTERS (spill-proof:
// r16's array-in-lambda form went to scratch, WRITE_SIZE 37->254 MB) after
// the L1 phase — global latency hides under H1+H2. No barriers.
// Bit-identical arithmetic to rounds 4/10/12 (absmax 0.25).
// ---------------------------------------------------------------------------
__global__ __launch_bounds__(WPB * 64, 1) void gmlp_kernel(
    const float* __restrict__ x,
    const float* __restrict__ embT,
    const float* __restrict__ gW1, const float* __restrict__ gb1,
    const float* __restrict__ gWh, const float* __restrict__ gbh,
    const float* __restrict__ gW2, const float* __restrict__ gb2,
    float* __restrict__ resid, float* __restrict__ logd)
{
    __shared__ __align__(16) float zb[WPB][128 * ZSTR];   // 8*18432 B = 147456 B
    // -> 1 block/CU, 8 waves (2 per SIMD)

    const int tid  = threadIdx.x;
    const int lane = tid & 63;
    const int w    = tid >> 6;
    const int d    = blockIdx.y;
    const int g0   = (blockIdx.x * WPB + w) * GPW;   // 128 blocks/d * 8 * 4 = 4096 slots

    float* Z = zb[w];
    const int sg = lane >> 3;   // s-block (4 samples each)
    const int jg = lane & 7;    // j-block (8 neurons each)

    // ---- loop-invariant weight/bias bases ----
    const float* W1 = gW1 + (size_t)d * GIN * HH + jg * 8;
    const float* Whg = gWh + (size_t)d * 2 * HH * HH;
    const float4 b1a = *(const float4*)&gb1[d * HH + jg * 8];
    const float4 b1b = *(const float4*)&gb1[d * HH + jg * 8 + 4];
    const float4 bh0a = *(const float4*)&gbh[(d * 2 + 0) * HH + jg * 8];
    const float4 bh0b = *(const float4*)&gbh[(d * 2 + 0) * HH + jg * 8 + 4];
    const float4 bh1a = *(const float4*)&gbh[(d * 2 + 1) * HH + jg * 8];
    const float4 bh1b = *(const float4*)&gbh[(d * 2 + 1) * HH + jg * 8 + 4];
    const float4 w2a = *(const float4*)&gW2[d * HH + jg * 8];
    const float4 w2b = *(const float4*)&gW2[d * HH + jg * 8 + 4];
    const float b2 = gb2[d];

    // ---- register prefetch state: NAMED float4s (SSA-promotable) ----
    float4 pe0, pe1, pe2, pe3, pe4, pe5, pe6, pe7;   // emb k-major quads
    float4 pxA, pxB;                                 // lag elements
    float  pxt;                                      // x_t
    const int s_ = lane & 31, h_ = lane >> 5;

#define ISSUE_LOADS(gid_)                                                    \
    {                                                                        \
        const float* eb = embT + (size_t)(gid_) * 2048;                      \
        pe0 = *(const float4*)&eb[0 * 256 + lane * 4];                       \
        pe1 = *(const float4*)&eb[1 * 256 + lane * 4];                       \
        pe2 = *(const float4*)&eb[2 * 256 + lane * 4];                       \
        pe3 = *(const float4*)&eb[3 * 256 + lane * 4];                       \
        pe4 = *(const float4*)&eb[4 * 256 + lane * 4];                       \
        pe5 = *(const float4*)&eb[5 * 256 + lane * 4];                       \
        pe6 = *(const float4*)&eb[6 * 256 + lane * 4];                       \
        pe7 = *(const float4*)&eb[7 * 256 + lane * 4];                       \
        const int n_ = (gid_) * 32 + s_;                                     \
        const int b_ = n_ / LLEN, l_ = n_ - b_ * LLEN;                       \
        const float* xp = x + ((size_t)(b_ * TT + l_)) * DD;                 \
        pxA = *(const float4*)(xp + h_ * 8);                                 \
        pxB = *(const float4*)(xp + h_ * 8 + 4);                             \
        pxt = xp[16 + d];                                                    \
    }

#define WRITE_ZIN()                                                          \
    {                                                                        \
        const int rr = lane >> 3, cc = lane & 7;                             \
        *(float4*)&Z[zoff( 0 + rr, cc)] = pe0;                               \
        *(float4*)&Z[zoff( 8 + rr, cc)] = pe1;                               \
        *(float4*)&Z[zoff(16 + rr, cc)] = pe2;                               \
        *(float4*)&Z[zoff(24 + rr, cc)] = pe3;                               \
        *(float4*)&Z[zoff(32 + rr, cc)] = pe4;                               \
        *(float4*)&Z[zoff(40 + rr, cc)] = pe5;                               \
        *(float4*)&Z[zoff(48 + rr, cc)] = pe6;                               \
        *(float4*)&Z[zoff(56 + rr, cc)] = pe7;                               \
        const int sb_ = s_ >> 2, se_ = s_ & 3, R0 = 64 + h_ * 8;             \
        Z[zoff(R0 + 0, sb_) + se_] = pxA.x;                                  \
        Z[zoff(R0 + 1, sb_) + se_] = pxA.y;                                  \
        Z[zoff(R0 + 2, sb_) + se_] = pxA.z;                                  \
        Z[zoff(R0 + 3, sb_) + se_] = pxA.w;                                  \
        Z[zoff(R0 + 4, sb_) + se_] = pxB.x;                                  \
        Z[zoff(R0 + 5, sb_) + se_] = pxB.y;                                  \
        Z[zoff(R0 + 6, sb_) + se_] = pxB.z;                                  \
        Z[zoff(R0 + 7, sb_) + se_] = pxB.w;                                  \
        if (h_ == 0) Z[zoff(80, sb_) + se_] = pxt;                           \
    }

    if (g0 < NG) ISSUE_LOADS(g0);

    for (int g = 0; g < GPW; ++g) {
        const int gid = g0 + g;
        if (gid >= NG) break;                    // wave-uniform
        const int n0 = gid * 32;

        WRITE_ZIN();                             // current group's staged regs -> Z

        // ---- L1: 81 -> 64, forward only ----
        float f[4][8];
#pragma unroll
        for (int si = 0; si < 4; ++si) {
            f[si][0] = b1a.x; f[si][1] = b1a.y; f[si][2] = b1a.z; f[si][3] = b1a.w;
            f[si][4] = b1b.x; f[si][5] = b1b.y; f[si][6] = b1b.z; f[si][7] = b1b.w;
        }
        __builtin_amdgcn_s_setprio(1);
#pragma unroll 8
        for (int k = 0; k < GIN; ++k) {
            const float4 wa = *(const float4*)&W1[(size_t)k * HH];
            const float4 wb = *(const float4*)&W1[(size_t)k * HH + 4];
            const float4 zq = *(const float4*)&Z[zoff(k, sg)];
            const float zs[4] = { zq.x, zq.y, zq.z, zq.w };
#pragma unroll
            for (int si = 0; si < 4; ++si) {
                f[si][0] = fmaf(zs[si], wa.x, f[si][0]);
                f[si][1] = fmaf(zs[si], wa.y, f[si][1]);
                f[si][2] = fmaf(zs[si], wa.z, f[si][2]);
                f[si][3] = fmaf(zs[si], wa.w, f[si][3]);
                f[si][4] = fmaf(zs[si], wb.x, f[si][4]);
                f[si][5] = fmaf(zs[si], wb.y, f[si][5]);
                f[si][6] = fmaf(zs[si], wb.z, f[si][6]);
                f[si][7] = fmaf(zs[si], wb.w, f[si][7]);
            }
        }
        __builtin_amdgcn_s_setprio(0);

        // ---- act + JVP seed; transpose-publish z (rows j), dz (rows 64+j) ----
        {
            const float4 w80a = *(const float4*)&W1[80 * HH];
            const float4 w80b = *(const float4*)&W1[80 * HH + 4];
            const float w80[8] = { w80a.x, w80a.y, w80a.z, w80a.w,
                                   w80b.x, w80b.y, w80b.z, w80b.w };
            float zv[4][8], dv[4][8];
#pragma unroll
            for (int si = 0; si < 4; ++si)
#pragma unroll
                for (int jj = 0; jj < 8; ++jj) {
                    const float m = (f[si][jj] >= 0.f) ? 1.f : 0.1f;
                    zv[si][jj] = f[si][jj] * m;
                    dv[si][jj] = w80[jj] * m;
                }
#pragma unroll
            for (int jj = 0; jj < 8; ++jj) {
                const int row = jg * 8 + jj;
                float4 q = { zv[0][jj], zv[1][jj], zv[2][jj], zv[3][jj] };
                *(float4*)&Z[zoff(row, sg)] = q;
                float4 p = { dv[0][jj], dv[1][jj], dv[2][jj], dv[3][jj] };
                *(float4*)&Z[zoff(64 + row, sg)] = p;
            }
        }

        // ---- prefetch next group's inputs (latency hides under H1+H2) ----
        if (g + 1 < GPW && gid + 1 < NG) ISSUE_LOADS(gid + 1);

        // ---- hidden layers: fused forward + JVP ----
        float ff[4][8], dd[4][8];
#pragma unroll
        for (int hl = 0; hl < 2; ++hl) {
            const float* Wl = Whg + hl * (HH * HH) + jg * 8;
            const float4 ba = hl ? bh1a : bh0a;
            const float4 bb = hl ? bh1b : bh0b;
#pragma unroll
            for (int si = 0; si < 4; ++si) {
                ff[si][0] = ba.x; ff[si][1] = ba.y; ff[si][2] = ba.z; ff[si][3] = ba.w;
                ff[si][4] = bb.x; ff[si][5] = bb.y; ff[si][6] = bb.z; ff[si][7] = bb.w;
#pragma unroll
                for (int jj = 0; jj < 8; ++jj) dd[si][jj] = 0.f;
            }
            __builtin_amdgcn_s_setprio(1);
#pragma unroll 8
            for (int k = 0; k < HH; ++k) {
                const float4 wa = *(const float4*)&Wl[k * HH];
                const float4 wb = *(const float4*)&Wl[k * HH + 4];
                const float4 zq = *(const float4*)&Z[zoff(k, sg)];
                const float4 dq = *(const float4*)&Z[zoff(64 + k, sg)];
                const float zs[4] = { zq.x, zq.y, zq.z, zq.w };
                const float ds[4] = { dq.x, dq.y, dq.z, dq.w };
#pragma unroll
                for (int si = 0; si < 4; ++si) {
                    ff[si][0] = fmaf(zs[si], wa.x, ff[si][0]);  dd[si][0] = fmaf(ds[si], wa.x, dd[si][0]);
                    ff[si][1] = fmaf(zs[si], wa.y, ff[si][1]);  dd[si][1] = fmaf(ds[si], wa.y, dd[si][1]);
                    ff[si][2] = fmaf(zs[si], wa.z, ff[si][2]);  dd[si][2] = fmaf(ds[si], wa.z, dd[si][2]);
                    ff[si][3] = fmaf(zs[si], wa.w, ff[si][3]);  dd[si][3] = fmaf(ds[si], wa.w, dd[si][3]);
                    ff[si][4] = fmaf(zs[si], wb.x, ff[si][4]);  dd[si][4] = fmaf(ds[si], wb.x, dd[si][4]);
                    ff[si][5] = fmaf(zs[si], wb.y, ff[si][5]);  dd[si][5] = fmaf(ds[si], wb.y, dd[si][5]);
                    ff[si][6] = fmaf(zs[si], wb.z, ff[si][6]);  dd[si][6] = fmaf(ds[si], wb.z, dd[si][6]);
                    ff[si][7] = fmaf(zs[si], wb.w, ff[si][7]);  dd[si][7] = fmaf(ds[si], wb.w, dd[si][7]);
                }
            }
            __builtin_amdgcn_s_setprio(0);
            // activation (in place)
#pragma unroll
            for (int si = 0; si < 4; ++si)
#pragma unroll
                for (int jj = 0; jj < 8; ++jj) {
                    const float m = (ff[si][jj] >= 0.f) ? 1.f : 0.1f;
                    ff[si][jj] *= m;
                    dd[si][jj] *= m;
                }
            if (hl == 0) {   // republish for H2
#pragma unroll
                for (int jj = 0; jj < 8; ++jj) {
                    const int row = jg * 8 + jj;
                    float4 q = { ff[0][jj], ff[1][jj], ff[2][jj], ff[3][jj] };
                    *(float4*)&Z[zoff(row, sg)] = q;
                    float4 p = { dd[0][jj], dd[1][jj], dd[2][jj], dd[3][jj] };
                    *(float4*)&Z[zoff(64 + row, sg)] = p;
                }
            }
        }

        // ---- final layer: 64 -> 1 (reduce over jg lanes) ----
        {
            float o[4], q[4];
#pragma unroll
            for (int si = 0; si < 4; ++si) {
                o[si] = ff[si][0]*w2a.x + ff[si][1]*w2a.y + ff[si][2]*w2a.z + ff[si][3]*w2a.w
                      + ff[si][4]*w2b.x + ff[si][5]*w2b.y + ff[si][6]*w2b.z + ff[si][7]*w2b.w;
                q[si] = dd[si][0]*w2a.x + dd[si][1]*w2a.y + dd[si][2]*w2a.z + dd[si][3]*w2a.w
                      + dd[si][4]*w2b.x + dd[si][5]*w2b.y + dd[si][6]*w2b.z + dd[si][7]*w2b.w;
#pragma unroll
                for (int m = 1; m <= 4; m <<= 1) {
                    o[si] += __shfl_xor(o[si], m);
                    q[si] += __shfl_xor(q[si], m);
                }
            }
            if (jg == 0) {
                const int nb = n0 + sg * 4;
                float4 lq;
                lq.x = __logf(fabsf(q[0])); lq.y = __logf(fabsf(q[1]));
                lq.z = __logf(fabsf(q[2])); lq.w = __logf(fabsf(q[3]));
#pragma unroll
                for (int si = 0; si < 4; ++si)
                    resid[(size_t)(nb + si) * DD + d] = o[si] + b2;
                *(float4*)&logd[(size_t)d * NN + nb] = lq;
            }
        }
    }
#undef ISSUE_LOADS
#undef WRITE_ZIN
}

// ---------------------------------------------------------------------------
// log-det reduction over d
// ---------------------------------------------------------------------------
__global__ __launch_bounds__(256) void reduce_kernel(
    const float* __restrict__ logd, float* __restrict__ out)
{
    const int n = blockIdx.x * 256 + threadIdx.x;
    if (n >= NN) return;
    float s = 0.f;
#pragma unroll
    for (int d = 0; d < DD; ++d) s += logd[(size_t)d * NN + n];
    out[n] = s;
}

extern "C" void kernel_launch(void* const* d_in, const int* in_sizes, int n_in,
                              void* d_out, int out_size, void* d_ws, size_t ws_size,
                              hipStream_t stream)
{
    const float* x          = (const float*)d_in[0];
    const float* embeddings = (const float*)d_in[1];
    const float* fcW1 = (const float*)d_in[2];
    const float* fcb1 = (const float*)d_in[3];
    const float* fcWh = (const float*)d_in[4];
    const float* fcbh = (const float*)d_in[5];
    const float* fcW2 = (const float*)d_in[6];
    const float* fcb2 = (const float*)d_in[7];
    const float* gW1  = (const float*)d_in[8];
    const float* gb1  = (const float*)d_in[9];
    const float* gWh  = (const float*)d_in[10];
    const float* gbh  = (const float*)d_in[11];
    const float* gW2  = (const float*)d_in[12];
    const float* gb2  = (const float*)d_in[13];

    float* out  = (float*)d_out;
    float* embT = (float*)d_ws;                         // NN*64 floats (k-major groups)
    float* logd = embT + (size_t)NN * HH;               // NN*8 floats

    emb_mlp_kernel<<<dim3(NN / 192), 192, 0, stream>>>(
        embeddings, fcW1, fcb1, fcWh, fcbh, fcW2, fcb2, embT);

    // 128 blocks/d x 8 waves x 4 groups = 4096 group-slots >= 4092
    gmlp_kernel<<<dim3((NG + WPB * GPW - 1) / (WPB * GPW), DD), WPB * 64, 0, stream>>>(
        x, embT, gW1, gb1, gWh, gbh, gW2, gb2, out, logd);

    reduce_kernel<<<dim3((NN + 255) / 256), 256, 0, stream>>>(
        logd, out + (size_t)NN * DD);
}

// Round 18
// 655.362 us; speedup vs baseline: 1.2088x; 1.1034x over previous
//
#include <hip/hip_runtime.h>
#include <hip/hip_bf16.h>
#include <math.h>

// Problem constants
#define BB   64
#define TT   2048
#define DD   8        // LATENT
#define HH   64       // HID
#define LLEN 2046     // length = TT - LAGS
#define NN   (BB*LLEN) // 130944 = 32*4092
#define GIN  81       // HID + LAGS*LATENT + 1

#define NG   (NN/32)  // 4092 sample-groups of 32
#define WPB  4        // waves per block (256 threads): 73.7 KB LDS -> 2 blocks/CU
#define ZSTR 36       // padded LDS row stride (dwords, 16B-aligned)

// swizzled LDS offset: row-major [128][ZSTR], s-block slot rotated by row>>3
// (HW-validated: 1.05M conflict-cycles total — do not change)
__device__ __forceinline__ int zoff(int row, int sb) {
    return row * ZSTR + (((sb + (row >> 3)) & 7) << 2);
}

// ---------------------------------------------------------------------------
// Embedding MLP: thread per (b,t); writes embT[g][k][s] (k-major, 32-sample
// groups) so gmlp can stage coalesced without a transpose.
// ---------------------------------------------------------------------------
template<int K, bool ACT>
__device__ __forceinline__ void fwd_layer(float* zr,
                                          const float* __restrict__ W,
                                          const float* __restrict__ bias)
{
    float acc[HH];
#pragma unroll
    for (int j = 0; j < HH; ++j) acc[j] = bias[j];
    for (int k = 0; k < K; ++k) {
        const float zk = zr[k];
        const float* wr = W + k * HH;
#pragma unroll
        for (int j = 0; j < HH; ++j) acc[j] = fmaf(zk, wr[j], acc[j]);
    }
#pragma unroll
    for (int j = 0; j < HH; ++j) {
        float v = acc[j];
        if (ACT) v = (v >= 0.f) ? v : 0.1f * v;
        zr[j] = v;
    }
}

__global__ __launch_bounds__(192) void emb_mlp_kernel(
    const float* __restrict__ emb_in,
    const float* __restrict__ W1, const float* __restrict__ b1,
    const float* __restrict__ Wh, const float* __restrict__ bh,
    const float* __restrict__ W2, const float* __restrict__ b2,
    float* __restrict__ embT)
{
    __shared__ float zrow[192][65];
    const int tid = threadIdx.x;
    const int n = blockIdx.x * 192 + tid;          // 682*192 == NN exact
    const int b = n / LLEN;
    const int l = n - b * LLEN;
    float* zr = zrow[tid];

    const float* ep = emb_in + ((size_t)(b * TT + (l + 2))) * 8;
    {
        float4 e0 = *(const float4*)ep;
        float4 e1 = *(const float4*)(ep + 4);
        zr[0] = e0.x; zr[1] = e0.y; zr[2] = e0.z; zr[3] = e0.w;
        zr[4] = e1.x; zr[5] = e1.y; zr[6] = e1.z; zr[7] = e1.w;
    }

    fwd_layer<8,  true >(zr, W1, b1);
    fwd_layer<HH, true >(zr, Wh,            bh);
    fwd_layer<HH, true >(zr, Wh + HH * HH,  bh + HH);
    fwd_layer<HH, false>(zr, W2, b2);

    // embT[n>>5][k][n&31] — per k, 32 consecutive threads write 128B chunks
    float* op = embT + ((size_t)(n >> 5)) * 2048 + (n & 31);
#pragma unroll
    for (int j = 0; j < HH; ++j) op[j * 32] = zr[j];
}

// ---------------------------------------------------------------------------
// gmlp: one wave = one 32-sample group (for block's d). Lane (sg,jg) owns a
// 4-sample x 8-neuron tile; per k: 1 z-quad + 1 dz-quad from swizzled LDS
// (broadcast, conflict-free) + 2 weight float4s from GLOBAL (L1-resident,
// 8-way broadcast addresses). No barriers; waves autonomous.
// WPB=4: 2 independent blocks/CU -> staging of one block overlaps compute of
// the other; grid 1023 blocks/d x 4 waves = 4092 = NG exact (no guard).
// Per-wave code identical to round 12 -> bit-identical results (absmax 0.25).
// ---------------------------------------------------------------------------
__global__ __launch_bounds__(WPB * 64, 2) void gmlp_kernel(
    const float* __restrict__ x,
    const float* __restrict__ embT,
    const float* __restrict__ gW1, const float* __restrict__ gb1,
    const float* __restrict__ gWh, const float* __restrict__ gbh,
    const float* __restrict__ gW2, const float* __restrict__ gb2,
    float* __restrict__ resid, float* __restrict__ logd)
{
    __shared__ __align__(16) float zb[WPB][128 * ZSTR];   // 4*18432 B = 73728 B
    // -> 2 blocks/CU, 8 waves/CU (2 per SIMD)

    const int tid  = threadIdx.x;
    const int lane = tid & 63;
    const int w    = tid >> 6;
    const int d    = blockIdx.y;
    const int gid  = blockIdx.x * WPB + w;       // 1023*4 = 4092 == NG exact

    float* Z = zb[w];
    const int sg = lane >> 3;   // s-block (4 samples each)
    const int jg = lane & 7;    // j-block (8 neurons each)
    const int n0 = gid * 32;

    // ---- stage emb rows 0..63: coalesced b128, swizzled LDS writes ----
    const float* eb = embT + (size_t)gid * 2048;
#pragma unroll
    for (int i = 0; i < 8; ++i) {
        float4 v = *(const float4*)&eb[i * 256 + lane * 4];
        const int row = i * 8 + (lane >> 3);   // row>>3 == i
        *(float4*)&Z[zoff(row, lane & 7)] = v;
    }
    // ---- stage lag rows 64..79 and x_t row 80 ----
    {
        const int s = lane & 31, h = lane >> 5;
        const int n = n0 + s;
        const int b = n / LLEN, l = n - b * LLEN;
        const float* xp = x + ((size_t)(b * TT + l)) * DD;
        float4 xv0 = *(const float4*)(xp + h * 8);
        float4 xv1 = *(const float4*)(xp + h * 8 + 4);
        float xv[8] = { xv0.x, xv0.y, xv0.z, xv0.w, xv1.x, xv1.y, xv1.z, xv1.w };
#pragma unroll
        for (int r = 0; r < 8; ++r) {
            const int R = 64 + h * 8 + r;
            Z[zoff(R, s >> 2) + (s & 3)] = xv[r];
        }
        if (h == 0) {
            const float xt = xp[16 + d];
            Z[zoff(80, s >> 2) + (s & 3)] = xt;
        }
    }

    // ---- biases / weight bases ----
    const float* W1 = gW1 + (size_t)d * GIN * HH + jg * 8;
    const float4 b1a = *(const float4*)&gb1[d * HH + jg * 8];
    const float4 b1b = *(const float4*)&gb1[d * HH + jg * 8 + 4];

    float f[4][8];
#pragma unroll
    for (int si = 0; si < 4; ++si) {
        f[si][0] = b1a.x; f[si][1] = b1a.y; f[si][2] = b1a.z; f[si][3] = b1a.w;
        f[si][4] = b1b.x; f[si][5] = b1b.y; f[si][6] = b1b.z; f[si][7] = b1b.w;
    }

    // ---- L1: 81 -> 64, forward only (weights streamed from global/L1) ----
    __builtin_amdgcn_s_setprio(1);
#pragma unroll 8
    for (int k = 0; k < GIN; ++k) {
        const float4 wa = *(const float4*)&W1[(size_t)k * HH];
        const float4 wb = *(const float4*)&W1[(size_t)k * HH + 4];
        const float4 zq = *(const float4*)&Z[zoff(k, sg)];
        const float zs[4] = { zq.x, zq.y, zq.z, zq.w };
#pragma unroll
        for (int si = 0; si < 4; ++si) {
            f[si][0] = fmaf(zs[si], wa.x, f[si][0]);
            f[si][1] = fmaf(zs[si], wa.y, f[si][1]);
            f[si][2] = fmaf(zs[si], wa.z, f[si][2]);
            f[si][3] = fmaf(zs[si], wa.w, f[si][3]);
            f[si][4] = fmaf(zs[si], wb.x, f[si][4]);
            f[si][5] = fmaf(zs[si], wb.y, f[si][5]);
            f[si][6] = fmaf(zs[si], wb.z, f[si][6]);
            f[si][7] = fmaf(zs[si], wb.w, f[si][7]);
        }
    }
    __builtin_amdgcn_s_setprio(0);

    // ---- act + JVP seed; transpose-publish z (rows j) and dz (rows 64+j) ----
    {
        const float4 w80a = *(const float4*)&W1[80 * HH];
        const float4 w80b = *(const float4*)&W1[80 * HH + 4];
        const float w80[8] = { w80a.x, w80a.y, w80a.z, w80a.w,
                               w80b.x, w80b.y, w80b.z, w80b.w };
        float zv[4][8], dv[4][8];
#pragma unroll
        for (int si = 0; si < 4; ++si)
#pragma unroll
            for (int jj = 0; jj < 8; ++jj) {
                const float m = (f[si][jj] >= 0.f) ? 1.f : 0.1f;
                zv[si][jj] = f[si][jj] * m;
                dv[si][jj] = w80[jj] * m;
            }
#pragma unroll
        for (int jj = 0; jj < 8; ++jj) {
            const int row = jg * 8 + jj;
            float4 q = { zv[0][jj], zv[1][jj], zv[2][jj], zv[3][jj] };
            *(float4*)&Z[zoff(row, sg)] = q;
            float4 p = { dv[0][jj], dv[1][jj], dv[2][jj], dv[3][jj] };
            *(float4*)&Z[zoff(64 + row, sg)] = p;
        }
    }

    // ---- hidden layers: fused forward + JVP, weights from global/L1 ----
    const float* Whg = gWh + (size_t)d * 2 * HH * HH;
    float ff[4][8], dd[4][8];
#pragma unroll
    for (int hl = 0; hl < 2; ++hl) {
        const float* Wl = Whg + hl * (HH * HH) + jg * 8;
        const float4 ba = *(const float4*)&gbh[(d * 2 + hl) * HH + jg * 8];
        const float4 bb = *(const float4*)&gbh[(d * 2 + hl) * HH + jg * 8 + 4];
#pragma unroll
        for (int si = 0; si < 4; ++si) {
            ff[si][0] = ba.x; ff[si][1] = ba.y; ff[si][2] = ba.z; ff[si][3] = ba.w;
            ff[si][4] = bb.x; ff[si][5] = bb.y; ff[si][6] = bb.z; ff[si][7] = bb.w;
#pragma unroll
            for (int jj = 0; jj < 8; ++jj) dd[si][jj] = 0.f;
        }
        __builtin_amdgcn_s_setprio(1);
#pragma unroll 8
        for (int k = 0; k < HH; ++k) {
            const float4 wa = *(const float4*)&Wl[k * HH];
            const float4 wb = *(const float4*)&Wl[k * HH + 4];
            const float4 zq = *(const float4*)&Z[zoff(k, sg)];
            const float4 dq = *(const float4*)&Z[zoff(64 + k, sg)];
            const float zs[4] = { zq.x, zq.y, zq.z, zq.w };
            const float ds[4] = { dq.x, dq.y, dq.z, dq.w };
#pragma unroll
            for (int si = 0; si < 4; ++si) {
                ff[si][0] = fmaf(zs[si], wa.x, ff[si][0]);  dd[si][0] = fmaf(ds[si], wa.x, dd[si][0]);
                ff[si][1] = fmaf(zs[si], wa.y, ff[si][1]);  dd[si][1] = fmaf(ds[si], wa.y, dd[si][1]);
                ff[si][2] = fmaf(zs[si], wa.z, ff[si][2]);  dd[si][2] = fmaf(ds[si], wa.z, dd[si][2]);
                ff[si][3] = fmaf(zs[si], wa.w, ff[si][3]);  dd[si][3] = fmaf(ds[si], wa.w, dd[si][3]);
                ff[si][4] = fmaf(zs[si], wb.x, ff[si][4]);  dd[si][4] = fmaf(ds[si], wb.x, dd[si][4]);
                ff[si][5] = fmaf(zs[si], wb.y, ff[si][5]);  dd[si][5] = fmaf(ds[si], wb.y, dd[si][5]);
                ff[si][6] = fmaf(zs[si], wb.z, ff[si][6]);  dd[si][6] = fmaf(ds[si], wb.z, dd[si][6]);
                ff[si][7] = fmaf(zs[si], wb.w, ff[si][7]);  dd[si][7] = fmaf(ds[si], wb.w, dd[si][7]);
            }
        }
        __builtin_amdgcn_s_setprio(0);
        // activation (in place)
#pragma unroll
        for (int si = 0; si < 4; ++si)
#pragma unroll
            for (int jj = 0; jj < 8; ++jj) {
                const float m = (ff[si][jj] >= 0.f) ? 1.f : 0.1f;
                ff[si][jj] *= m;
                dd[si][jj] *= m;
            }
        if (hl == 0) {   // republish for H2 (all reads of this buffer are done)
#pragma unroll
            for (int jj = 0; jj < 8; ++jj) {
                const int row = jg * 8 + jj;
                float4 q = { ff[0][jj], ff[1][jj], ff[2][jj], ff[3][jj] };
                *(float4*)&Z[zoff(row, sg)] = q;
                float4 p = { dd[0][jj], dd[1][jj], dd[2][jj], dd[3][jj] };
                *(float4*)&Z[zoff(64 + row, sg)] = p;
            }
        }
    }

    // ---- final layer: 64 -> 1 (reduce over jg lanes) ----
    {
        const float4 w2a = *(const float4*)&gW2[d * HH + jg * 8];
        const float4 w2b = *(const float4*)&gW2[d * HH + jg * 8 + 4];
        const float b2 = gb2[d];
        float o[4], q[4];
#pragma unroll
        for (int si = 0; si < 4; ++si) {
            o[si] = ff[si][0]*w2a.x + ff[si][1]*w2a.y + ff[si][2]*w2a.z + ff[si][3]*w2a.w
                  + ff[si][4]*w2b.x + ff[si][5]*w2b.y + ff[si][6]*w2b.z + ff[si][7]*w2b.w;
            q[si] = dd[si][0]*w2a.x + dd[si][1]*w2a.y + dd[si][2]*w2a.z + dd[si][3]*w2a.w
                  + dd[si][4]*w2b.x + dd[si][5]*w2b.y + dd[si][6]*w2b.z + dd[si][7]*w2b.w;
#pragma unroll
            for (int m = 1; m <= 4; m <<= 1) {
                o[si] += __shfl_xor(o[si], m);
                q[si] += __shfl_xor(q[si], m);
            }
        }
        if (jg == 0) {
            const int nb = n0 + sg * 4;
            float4 lq;
            lq.x = __logf(fabsf(q[0])); lq.y = __logf(fabsf(q[1]));
            lq.z = __logf(fabsf(q[2])); lq.w = __logf(fabsf(q[3]));
#pragma unroll
            for (int si = 0; si < 4; ++si)
                resid[(size_t)(nb + si) * DD + d] = o[si] + b2;
            *(float4*)&logd[(size_t)d * NN + nb] = lq;
        }
    }
}

// ---------------------------------------------------------------------------
// log-det reduction over d
// ---------------------------------------------------------------------------
__global__ __launch_bounds__(256) void reduce_kernel(
    const float* __restrict__ logd, float* __restrict__ out)
{
    const int n = blockIdx.x * 256 + threadIdx.x;
    if (n >= NN) return;
    float s = 0.f;
#pragma unroll
    for (int d = 0; d < DD; ++d) s += logd[(size_t)d * NN + n];
    out[n] = s;
}

extern "C" void kernel_launch(void* const* d_in, const int* in_sizes, int n_in,
                              void* d_out, int out_size, void* d_ws, size_t ws_size,
                              hipStream_t stream)
{
    const float* x          = (const float*)d_in[0];
    const float* embeddings = (const float*)d_in[1];
    const float* fcW1 = (const float*)d_in[2];
    const float* fcb1 = (const float*)d_in[3];
    const float* fcWh = (const float*)d_in[4];
    const float* fcbh = (const float*)d_in[5];
    const float* fcW2 = (const float*)d_in[6];
    const float* fcb2 = (const float*)d_in[7];
    const float* gW1  = (const float*)d_in[8];
    const float* gb1  = (const float*)d_in[9];
    const float* gWh  = (const float*)d_in[10];
    const float* gbh  = (const float*)d_in[11];
    const float* gW2  = (const float*)d_in[12];
    const float* gb2  = (const float*)d_in[13];

    float* out  = (float*)d_out;
    float* embT = (float*)d_ws;                         // NN*64 floats (k-major groups)
    float* logd = embT + (size_t)NN * HH;               // NN*8 floats

    emb_mlp_kernel<<<dim3(NN / 192), 192, 0, stream>>>(
        embeddings, fcW1, fcb1, fcWh, fcbh, fcW2, fcb2, embT);

    // 1023 blocks/d x 4 waves = 4092 wave-groups == NG exact
    gmlp_kernel<<<dim3(NG / WPB, DD), WPB * 64, 0, stream>>>(
        x, embT, gW1, gb1, gWh, gbh, gW2, gb2, out, logd);

    reduce_kernel<<<dim3((NN + 255) / 256), 256, 0, stream>>>(
        logd, out + (size_t)NN * DD);
}